// Round 5
// baseline (388.679 us; speedup 1.0000x reference)
//
#include <hip/hip_runtime.h>
#include <stdint.h>

typedef unsigned short u16;
typedef __bf16 bf16_t;
typedef bf16_t bf16x8 __attribute__((ext_vector_type(8)));
typedef float f32x4 __attribute__((ext_vector_type(4)));

__device__ __forceinline__ float b2f(u16 u) {
  union { unsigned int i; float f; } v; v.i = ((unsigned int)u) << 16; return v.f;
}
__device__ __forceinline__ u16 f2b(float f) {
  union { float f; unsigned int i; } v; v.f = f;
  unsigned int r = v.i + 0x7fffu + ((v.i >> 16) & 1u);  // RNE
  return (u16)(r >> 16);
}
__device__ __forceinline__ unsigned int pk2(float a, float b) {
  return (unsigned int)f2b(a) | ((unsigned int)f2b(b) << 16);
}
__device__ __forceinline__ void async16(const void* g, void* lds) {
  __builtin_amdgcn_global_load_lds((const __attribute__((address_space(1))) void*)g,
                                   (__attribute__((address_space(3))) void*)lds,
                                   16, 0, 0);
}

// ---------------- fp32 -> bf16 conversion ----------------
__global__ void k_f2b(const float* __restrict__ src, u16* __restrict__ dst, int n) {
  int i = (blockIdx.x * 256 + threadIdx.x) * 4;
  int stride = gridDim.x * 256 * 4;
  for (; i < n; i += stride) {
    float4 v = *reinterpret_cast<const float4*>(src + i);
    u16 o[4] = { f2b(v.x), f2b(v.y), f2b(v.z), f2b(v.w) };
    *reinterpret_cast<uint2*>(dst + i) = *reinterpret_cast<uint2*>(o);
  }
}

// ---------------- GEMM: C = A(MxK) * B(NxK)^T, bf16 in, f32 or bf16 out ----------------
__device__ __forceinline__ void xcd_tile(int ntx, int* m0, int* n0) {
  int id = blockIdx.y * ntx + blockIdx.x;
  int nwg = ntx * gridDim.y;
  if ((nwg & 7) == 0) {
    int q = nwg >> 3;
    id = (id & 7) * q + (id >> 3);
  }
  *m0 = (id / ntx) * 128;
  *n0 = (id % ntx) * 128;
}

template<int OUT_BF16>
__device__ __forceinline__ void gemm_core(const u16* __restrict__ A, const u16* __restrict__ B,
                                          void* __restrict__ Cv, int M, int N, int K,
                                          int m0, int n0) {
  __shared__ __align__(16) u16 As[128 * 32];
  __shared__ __align__(16) u16 Bs[128 * 32];
  const int tid = threadIdx.x, lane = tid & 63, w = tid >> 6;
  const int wr = (w >> 1) * 64, wc = (w & 1) * 64;
  const int lr = lane & 15, lk = (lane >> 4) * 8;
  f32x4 acc[4][4] = {};
  for (int k0 = 0; k0 < K; k0 += 32) {
    if (k0) __syncthreads();
#pragma unroll
    for (int it = 0; it < 2; ++it) {
      int c = it * 256 + tid;
      int row = c >> 2, kc = (c & 3) * 8;
      async16(A + (size_t)(m0 + row) * K + k0 + kc, (char*)As + c * 16);
      async16(B + (size_t)(n0 + row) * K + k0 + kc, (char*)Bs + c * 16);
    }
    __syncthreads();
    bf16x8 af[4], bfr[4];
#pragma unroll
    for (int i = 0; i < 4; ++i)
      af[i] = *reinterpret_cast<const bf16x8*>(&As[(wr + i * 16 + lr) * 32 + lk]);
#pragma unroll
    for (int i = 0; i < 4; ++i)
      bfr[i] = *reinterpret_cast<const bf16x8*>(&Bs[(wc + i * 16 + lr) * 32 + lk]);
#pragma unroll
    for (int i = 0; i < 4; ++i)
#pragma unroll
      for (int j = 0; j < 4; ++j)
        acc[i][j] = __builtin_amdgcn_mfma_f32_16x16x32_bf16(af[i], bfr[j], acc[i][j], 0, 0, 0);
  }
  const int er = (lane >> 4) * 4, ec = lane & 15;
#pragma unroll
  for (int i = 0; i < 4; ++i)
#pragma unroll
    for (int j = 0; j < 4; ++j)
#pragma unroll
      for (int jj = 0; jj < 4; ++jj) {
        int r = m0 + wr + i * 16 + er + jj;
        int cc = n0 + wc + j * 16 + ec;
        if (OUT_BF16) ((u16*)Cv)[(size_t)r * N + cc] = f2b(acc[i][j][jj]);
        else          ((float*)Cv)[(size_t)r * N + cc] = acc[i][j][jj];
      }
}

__global__ __launch_bounds__(256) void k_gemm_bf16(const u16* A, const u16* B, u16* C,
                                                   int M, int N, int K) {
  int m0, n0; xcd_tile(gridDim.x, &m0, &n0);
  gemm_core<1>(A, B, C, M, N, K, m0, n0);
}
__global__ __launch_bounds__(256) void k_gemm_f32(const u16* A, const u16* B, float* C,
                                                  int M, int N, int K) {
  int m0, n0; xcd_tile(gridDim.x, &m0, &n0);
  gemm_core<0>(A, B, C, M, N, K, m0, n0);
}
__global__ __launch_bounds__(256) void k_gemm_kv(const u16* A, const u16* Bk, const u16* Bv,
                                                 u16* Ck, u16* Cvp, int M, int N, int K) {
  const u16* B = blockIdx.z ? Bv : Bk;
  u16* C = blockIdx.z ? Cvp : Ck;
  int m0, n0; xcd_tile(gridDim.x, &m0, &n0);
  gemm_core<1>(A, B, C, M, N, K, m0, n0);
}

// ---------------- RMSNorm(offset) + RoPE (+ optional post-scale), in place ----------------
__global__ __launch_bounds__(256) void k_normrope(u16* __restrict__ buf,
                                                  const float* __restrict__ cosb,
                                                  const float* __restrict__ sinb,
                                                  const float* __restrict__ w,
                                                  int nheads, int rowstride, int headstride,
                                                  int total, float post_scale) {
  int wid = blockIdx.x * 4 + (threadIdx.x >> 6);
  int lane = threadIdx.x & 63;
  int t = wid / nheads, h = wid - t * nheads;
  if (t >= total) return;
  u16* base = buf + (size_t)t * rowstride + h * headstride;
  float a = b2f(base[lane]), b = b2f(base[lane + 64]);
  float ss = a * a + b * b;
#pragma unroll
  for (int m = 32; m >= 1; m >>= 1) ss += __shfl_xor(ss, m, 64);
  float r = rsqrtf(ss * (1.0f / 128.0f) + 1e-6f);
  float qa = (1.0f + w[lane]) * a * r;
  float qb = (1.0f + w[lane + 64]) * b * r;
  const float* cr = cosb + (size_t)t * 128;
  const float* sr = sinb + (size_t)t * 128;
  float oa = (qa * cr[lane] - qb * sr[lane]) * post_scale;
  float ob = (qb * cr[lane + 64] + qa * sr[lane + 64]) * post_scale;
  base[lane] = f2b(oa);
  base[lane + 64] = f2b(ob);
}

// ---------------- transpose (rows x cols) -> (cols x rows), bf16 ----------------
__global__ __launch_bounds__(256) void k_transpose(const u16* __restrict__ src,
                                                   u16* __restrict__ dst, int rows, int cols) {
  __shared__ u16 tile[32][33];
  int bx = blockIdx.x * 32, by = blockIdx.y * 32;
  int tx = threadIdx.x & 31, ty = threadIdx.x >> 5;
#pragma unroll
  for (int i = 0; i < 4; ++i)
    tile[ty + i * 8][tx] = src[(size_t)(bx + ty + i * 8) * cols + by + tx];
  __syncthreads();
#pragma unroll
  for (int i = 0; i < 4; ++i)
    dst[(size_t)(by + ty + i * 8) * rows + bx + tx] = tile[tx][ty + i * 8];
}

// ---------------- flash attention + gate: split-KV, KVBLK=64 ----------
// grid(total/16, H). Block = 16 q-rows of one head; 4 waves round-robin 64-wide KV tiles.
// Partials published to LDS in bf16, merged by LSE. q pre-scaled by (1/sqrt(D))*log2(e).
__global__ __launch_bounds__(256, 3) void k_attn(const u16* __restrict__ qg,  // total x 4096
                                                 const u16* __restrict__ kb,  // total x 512
                                                 const u16* __restrict__ vt,  // 512 x total
                                                 u16* __restrict__ outg,      // total x 2048
                                                 const int* __restrict__ cu, int n_seq, int total) {
  __shared__ __align__(16) u16 Ps[4][16][72];     // per-wave P tile [q][kv0..63], padded rows
  __shared__ __align__(16) u16 Lo[4][16][136];    // per-wave partial O^T, bf16, padded rows
  __shared__ float Lm[4][16], Ll[4][16];
  const int tid = threadIdx.x, lane = tid & 63, w = tid >> 6;
  const int h = blockIdx.y, kh = h >> 2;
  const int g = lane >> 4, l15 = lane & 15;

  // heavy-first q-tile remap (deepest causal tiles dispatched first)
  int bx = blockIdx.x, nt = gridDim.x, qt = bx;
  int per = total / n_seq;
  if (per * n_seq == total && (per & 15) == 0 && nt % n_seq == 0) {
    int tps = per >> 4;
    int seg = bx % n_seq;
    qt = seg * tps + (tps - 1 - bx / n_seq);
  }
  const int qr0 = qt * 16;

  int seg_start = 0, seg_end = total;
  for (int s = 0; s < n_seq; ++s) {
    int a = cu[s], b = cu[s + 1];
    if (qr0 >= a && qr0 < b) { seg_start = a; seg_end = b; }
  }
  const int qrow = qr0 + l15;

  // Q as B-fragment: col = q = l15, k = d
  bf16x8 qf[4];
#pragma unroll
  for (int cc = 0; cc < 4; ++cc)
    qf[cc] = *reinterpret_cast<const bf16x8*>(qg + (size_t)qrow * 4096 + h * 256 + cc * 32 + g * 8);

  f32x4 o[8] = {};                  // O^T partial: lane q = l15, d = db*16 + g*4 + reg
  float mrow = -1e30f, lrow = 0.f;
  const int kv_hi = (seg_end < qr0 + 16) ? seg_end : (qr0 + 16);
  const int ntiles = (kv_hi - seg_start + 63) >> 6;

  for (int t = w; t < ntiles; t += 4) {
    const int kv0 = seg_start + t * 64;
    // QK^T for 64 kv rows: 4 parallel 4-deep MFMA chains
    f32x4 sa[4] = {};
    int krow[4];
#pragma unroll
    for (int s = 0; s < 4; ++s) {
      int r = kv0 + s * 16 + l15;
      krow[s] = (r < total) ? r : (total - 1);
    }
#pragma unroll
    for (int cc = 0; cc < 4; ++cc) {
#pragma unroll
      for (int s = 0; s < 4; ++s) {
        bf16x8 kf = *reinterpret_cast<const bf16x8*>(kb + (size_t)krow[s] * 512 + kh * 128 + cc * 32 + g * 8);
        sa[s] = __builtin_amdgcn_mfma_f32_16x16x32_bf16(kf, qf[cc], sa[s], 0, 0, 0);
      }
    }
    // mask + in-lane max over the lane's 16 kv values
    float sv[16];
#pragma unroll
    for (int s = 0; s < 4; ++s)
#pragma unroll
      for (int j = 0; j < 4; ++j)
        sv[s * 4 + j] = (kv0 + s * 16 + g * 4 + j > qrow) ? -1e30f : sa[s][j];
    float pm = sv[0];
#pragma unroll
    for (int j = 1; j < 16; ++j) pm = fmaxf(pm, sv[j]);
    pm = fmaxf(pm, __shfl_xor(pm, 16));
    pm = fmaxf(pm, __shfl_xor(pm, 32));
    if (pm > mrow + 11.5f) {        // defer-max (~8 nats, log2 domain)
      float fs = __builtin_amdgcn_exp2f(mrow - pm);
      lrow *= fs;
#pragma unroll
      for (int db = 0; db < 8; ++db)
#pragma unroll
        for (int j = 0; j < 4; ++j) o[db][j] *= fs;
      mrow = pm;
    }
    float p[16];
#pragma unroll
    for (int j = 0; j < 16; ++j)
      p[j] = (sv[j] > -1e29f) ? __builtin_amdgcn_exp2f(sv[j] - mrow) : 0.0f;
    float ps = 0.f;
#pragma unroll
    for (int j = 0; j < 16; ++j) ps += p[j];
    ps += __shfl_xor(ps, 16);
    ps += __shfl_xor(ps, 32);
    lrow += ps;
    // P tile [q][kv] to LDS: 4x ds_write_b64 per lane
#pragma unroll
    for (int s = 0; s < 4; ++s) {
      uint2 pw = { pk2(p[s * 4], p[s * 4 + 1]), pk2(p[s * 4 + 2], p[s * 4 + 3]) };
      *reinterpret_cast<uint2*>(&Ps[w][l15][s * 16 + g * 4]) = pw;
    }
    asm volatile("" ::: "memory");  // in-wave DS write->read ordering
    // PV: O^T += V^T * P, 8 parallel 2-deep chains
    int vcol0 = kv0;
    if (vcol0 + 63 >= total) vcol0 = total - 64;
#pragma unroll
    for (int half = 0; half < 2; ++half) {
      bf16x8 pf = *reinterpret_cast<const bf16x8*>(&Ps[w][l15][half * 32 + g * 8]);
#pragma unroll
      for (int db = 0; db < 8; ++db) {
        bf16x8 vf = *reinterpret_cast<const bf16x8*>(
            vt + (size_t)(kh * 128 + db * 16 + l15) * total + vcol0 + half * 32 + g * 8);
        o[db] = __builtin_amdgcn_mfma_f32_16x16x32_bf16(vf, pf, o[db], 0, 0, 0);
      }
    }
  }

  // publish partials (bf16, padded rows)
#pragma unroll
  for (int db = 0; db < 8; ++db) {
    uint2 pw = { pk2(o[db][0], o[db][1]), pk2(o[db][2], o[db][3]) };
    *reinterpret_cast<uint2*>(&Lo[w][l15][db * 16 + g * 4]) = pw;
  }
  if (g == 0) { Lm[w][l15] = mrow; Ll[w][l15] = lrow; }
  __syncthreads();

  // combine: thread -> (q = tid&15, d group = (tid>>4)*8)
  const int q = tid & 15, dg = tid >> 4;
  float m0 = Lm[0][q], m1 = Lm[1][q], m2 = Lm[2][q], m3 = Lm[3][q];
  float M = fmaxf(fmaxf(m0, m1), fmaxf(m2, m3));
  float r0 = exp2f(m0 - M), r1 = exp2f(m1 - M), r2 = exp2f(m2 - M), r3 = exp2f(m3 - M);
  float L = Ll[0][q] * r0 + Ll[1][q] * r1 + Ll[2][q] * r2 + Ll[3][q] * r3;
  float invL = 1.0f / L;
  float rw[4] = { r0, r1, r2, r3 };
  float s[8] = {};
#pragma unroll
  for (int ww = 0; ww < 4; ++ww) {
    uint4 pr = *reinterpret_cast<const uint4*>(&Lo[ww][q][dg * 8]);
    unsigned int pu[4] = { pr.x, pr.y, pr.z, pr.w };
#pragma unroll
    for (int c = 0; c < 4; ++c) {
      s[c * 2]     += b2f((u16)(pu[c] & 0xffff)) * rw[ww];
      s[c * 2 + 1] += b2f((u16)(pu[c] >> 16)) * rw[ww];
    }
  }
  const int row = qr0 + q;
  const u16* gp = qg + (size_t)row * 4096 + h * 256 + 128 + dg * 8;
  uint4 gw = *reinterpret_cast<const uint4*>(gp);
  u16 gu[8] = { (u16)(gw.x & 0xffff), (u16)(gw.x >> 16), (u16)(gw.y & 0xffff), (u16)(gw.y >> 16),
                (u16)(gw.z & 0xffff), (u16)(gw.z >> 16), (u16)(gw.w & 0xffff), (u16)(gw.w >> 16) };
  u16 ou[8];
#pragma unroll
  for (int j = 0; j < 8; ++j) {
    float gate = b2f(gu[j]);
    float sig = 1.0f / (1.0f + __expf(-gate));
    ou[j] = f2b(s[j] * invL * sig);
  }
  *reinterpret_cast<uint4*>(outg + (size_t)row * 2048 + h * 128 + dg * 8) =
      *reinterpret_cast<uint4*>(ou);
}

extern "C" void kernel_launch(void* const* d_in, const int* in_sizes, int n_in,
                              void* d_out, int out_size, void* d_ws, size_t ws_size,
                              hipStream_t stream) {
  const float* x    = (const float*)d_in[0];
  const float* cosb = (const float*)d_in[1];
  const float* sinb = (const float*)d_in[2];
  const float* Wq   = (const float*)d_in[3];
  const float* Wk   = (const float*)d_in[4];
  const float* Wv   = (const float*)d_in[5];
  const float* Wo   = (const float*)d_in[6];
  const float* qnw  = (const float*)d_in[7];
  const float* knw  = (const float*)d_in[8];
  const int*   cu   = (const int*)d_in[9];
  const int n_seq = in_sizes[9] - 1;

  const int hidden = 2048, H = 16, KVH = 4, D = 128;
  const int total = in_sizes[0] / hidden;  // 4096
  const int NQ = H * D * 2;                // 4096
  const int NKV = KVH * D;                 // 512

  char* ws = (char*)d_ws;
  size_t off = 0;
  auto alloc = [&](size_t elems) {
    u16* p = (u16*)(ws + off);
    off += elems * 2;
    off = (off + 255) & ~(size_t)255;
    return p;
  };
  u16* xb   = alloc((size_t)total * hidden);
  u16* Wqb  = alloc((size_t)NQ * hidden);
  u16* Wkb  = alloc((size_t)NKV * hidden);
  u16* Wvb  = alloc((size_t)NKV * hidden);
  u16* Wob  = alloc((size_t)hidden * (H * D));
  u16* qgb  = alloc((size_t)total * NQ);
  u16* kbuf = alloc((size_t)total * NKV);
  u16* vbuf = alloc((size_t)total * NKV);
  u16* vtb  = alloc((size_t)total * NKV);
  u16* attg = Wqb;  // alias: Wqb dead after GEMM1

  auto cgrid = [](int n) { int g = (n / 4 + 255) / 256; return g > 2048 ? 2048 : g; };
  k_f2b<<<cgrid(total * hidden), 256, 0, stream>>>(x, xb, total * hidden);
  k_f2b<<<cgrid(NQ * hidden), 256, 0, stream>>>(Wq, Wqb, NQ * hidden);
  k_f2b<<<cgrid(NKV * hidden), 256, 0, stream>>>(Wk, Wkb, NKV * hidden);
  k_f2b<<<cgrid(NKV * hidden), 256, 0, stream>>>(Wv, Wvb, NKV * hidden);
  k_f2b<<<cgrid(hidden * H * D), 256, 0, stream>>>(Wo, Wob, hidden * H * D);

  k_gemm_bf16<<<dim3(NQ / 128, total / 128), 256, 0, stream>>>(xb, Wqb, qgb, total, NQ, hidden);
  k_gemm_kv<<<dim3(NKV / 128, total / 128, 2), 256, 0, stream>>>(xb, Wkb, Wvb, kbuf, vbuf,
                                                                 total, NKV, hidden);
  k_transpose<<<dim3(total / 32, NKV / 32), 256, 0, stream>>>(vbuf, vtb, total, NKV);
  const float qscale = 0.08838834764831845f * 1.4426950408889634f;  // 1/sqrt(D) * log2(e)
  k_normrope<<<total * H / 4, 256, 0, stream>>>(qgb, cosb, sinb, qnw, H, NQ, 2 * D, total, qscale);
  k_normrope<<<total * KVH / 4, 256, 0, stream>>>(kbuf, cosb, sinb, knw, KVH, NKV, D, total, 1.0f);
  k_attn<<<dim3(total / 16, H), 256, 0, stream>>>(qgb, kbuf, vtb, attg, cu, n_seq, total);
  k_gemm_f32<<<dim3(hidden / 128, total / 128), 256, 0, stream>>>(attg, Wob, (float*)d_out,
                                                                  total, hidden, H * D);
}

// Round 6
// 305.098 us; speedup vs baseline: 1.2739x; 1.2739x over previous
//
#include <hip/hip_runtime.h>
#include <stdint.h>

typedef unsigned short u16;
typedef __bf16 bf16_t;
typedef bf16_t bf16x8 __attribute__((ext_vector_type(8)));
typedef float f32x4 __attribute__((ext_vector_type(4)));

__device__ __forceinline__ float b2f(u16 u) {
  union { unsigned int i; float f; } v; v.i = ((unsigned int)u) << 16; return v.f;
}
__device__ __forceinline__ u16 f2b(float f) {
  union { float f; unsigned int i; } v; v.f = f;
  unsigned int r = v.i + 0x7fffu + ((v.i >> 16) & 1u);  // RNE
  return (u16)(r >> 16);
}
__device__ __forceinline__ unsigned int pk2(float a, float b) {
  return (unsigned int)f2b(a) | ((unsigned int)f2b(b) << 16);
}
__device__ __forceinline__ void async16(const void* g, void* lds) {
  __builtin_amdgcn_global_load_lds((const __attribute__((address_space(1))) void*)g,
                                   (__attribute__((address_space(3))) void*)lds,
                                   16, 0, 0);
}

// ---------------- fp32 -> bf16 conversion ----------------
__global__ void k_f2b(const float* __restrict__ src, u16* __restrict__ dst, int n) {
  int i = (blockIdx.x * 256 + threadIdx.x) * 4;
  int stride = gridDim.x * 256 * 4;
  for (; i < n; i += stride) {
    float4 v = *reinterpret_cast<const float4*>(src + i);
    u16 o[4] = { f2b(v.x), f2b(v.y), f2b(v.z), f2b(v.w) };
    *reinterpret_cast<uint2*>(dst + i) = *reinterpret_cast<uint2*>(o);
  }
}

// ---------------- GEMM: C = A(MxK) * B(NxK)^T, bf16 in, f32 or bf16 out ----------------
__device__ __forceinline__ void xcd_tile(int ntx, int* m0, int* n0) {
  int id = blockIdx.y * ntx + blockIdx.x;
  int nwg = ntx * gridDim.y;
  if ((nwg & 7) == 0) {
    int q = nwg >> 3;
    id = (id & 7) * q + (id >> 3);
  }
  *m0 = (id / ntx) * 128;
  *n0 = (id % ntx) * 128;
}

template<int OUT_BF16>
__device__ __forceinline__ void gemm_core(const u16* __restrict__ A, const u16* __restrict__ B,
                                          void* __restrict__ Cv, int M, int N, int K,
                                          int m0, int n0) {
  __shared__ __align__(16) u16 As[128 * 32];
  __shared__ __align__(16) u16 Bs[128 * 32];
  const int tid = threadIdx.x, lane = tid & 63, w = tid >> 6;
  const int wr = (w >> 1) * 64, wc = (w & 1) * 64;
  const int lr = lane & 15, lk = (lane >> 4) * 8;
  f32x4 acc[4][4] = {};
  for (int k0 = 0; k0 < K; k0 += 32) {
    if (k0) __syncthreads();
#pragma unroll
    for (int it = 0; it < 2; ++it) {
      int c = it * 256 + tid;
      int row = c >> 2, kc = (c & 3) * 8;
      async16(A + (size_t)(m0 + row) * K + k0 + kc, (char*)As + c * 16);
      async16(B + (size_t)(n0 + row) * K + k0 + kc, (char*)Bs + c * 16);
    }
    __syncthreads();
    bf16x8 af[4], bfr[4];
#pragma unroll
    for (int i = 0; i < 4; ++i)
      af[i] = *reinterpret_cast<const bf16x8*>(&As[(wr + i * 16 + lr) * 32 + lk]);
#pragma unroll
    for (int i = 0; i < 4; ++i)
      bfr[i] = *reinterpret_cast<const bf16x8*>(&Bs[(wc + i * 16 + lr) * 32 + lk]);
#pragma unroll
    for (int i = 0; i < 4; ++i)
#pragma unroll
      for (int j = 0; j < 4; ++j)
        acc[i][j] = __builtin_amdgcn_mfma_f32_16x16x32_bf16(af[i], bfr[j], acc[i][j], 0, 0, 0);
  }
  const int er = (lane >> 4) * 4, ec = lane & 15;
#pragma unroll
  for (int i = 0; i < 4; ++i)
#pragma unroll
    for (int j = 0; j < 4; ++j)
#pragma unroll
      for (int jj = 0; jj < 4; ++jj) {
        int r = m0 + wr + i * 16 + er + jj;
        int cc = n0 + wc + j * 16 + ec;
        if (OUT_BF16) ((u16*)Cv)[(size_t)r * N + cc] = f2b(acc[i][j][jj]);
        else          ((float*)Cv)[(size_t)r * N + cc] = acc[i][j][jj];
      }
}

__global__ __launch_bounds__(256) void k_gemm_bf16(const u16* A, const u16* B, u16* C,
                                                   int M, int N, int K) {
  int m0, n0; xcd_tile(gridDim.x, &m0, &n0);
  gemm_core<1>(A, B, C, M, N, K, m0, n0);
}
__global__ __launch_bounds__(256) void k_gemm_f32(const u16* A, const u16* B, float* C,
                                                  int M, int N, int K) {
  int m0, n0; xcd_tile(gridDim.x, &m0, &n0);
  gemm_core<0>(A, B, C, M, N, K, m0, n0);
}
__global__ __launch_bounds__(256) void k_gemm_kv(const u16* A, const u16* Bk, const u16* Bv,
                                                 u16* Ck, u16* Cvp, int M, int N, int K) {
  const u16* B = blockIdx.z ? Bv : Bk;
  u16* C = blockIdx.z ? Cvp : Ck;
  int m0, n0; xcd_tile(gridDim.x, &m0, &n0);
  gemm_core<1>(A, B, C, M, N, K, m0, n0);
}

// ---------------- RMSNorm(offset) + RoPE (+ optional post-scale), in place ----------------
__global__ __launch_bounds__(256) void k_normrope(u16* __restrict__ buf,
                                                  const float* __restrict__ cosb,
                                                  const float* __restrict__ sinb,
                                                  const float* __restrict__ w,
                                                  int nheads, int rowstride, int headstride,
                                                  int total, float post_scale) {
  int wid = blockIdx.x * 4 + (threadIdx.x >> 6);
  int lane = threadIdx.x & 63;
  int t = wid / nheads, h = wid - t * nheads;
  if (t >= total) return;
  u16* base = buf + (size_t)t * rowstride + h * headstride;
  float a = b2f(base[lane]), b = b2f(base[lane + 64]);
  float ss = a * a + b * b;
#pragma unroll
  for (int m = 32; m >= 1; m >>= 1) ss += __shfl_xor(ss, m, 64);
  float r = rsqrtf(ss * (1.0f / 128.0f) + 1e-6f);
  float qa = (1.0f + w[lane]) * a * r;
  float qb = (1.0f + w[lane + 64]) * b * r;
  const float* cr = cosb + (size_t)t * 128;
  const float* sr = sinb + (size_t)t * 128;
  float oa = (qa * cr[lane] - qb * sr[lane]) * post_scale;
  float ob = (qb * cr[lane + 64] + qa * sr[lane + 64]) * post_scale;
  base[lane] = f2b(oa);
  base[lane + 64] = f2b(ob);
}

// ---------------- transpose (rows x cols) -> (cols x rows), bf16 ----------------
__global__ __launch_bounds__(256) void k_transpose(const u16* __restrict__ src,
                                                   u16* __restrict__ dst, int rows, int cols) {
  __shared__ u16 tile[32][33];
  int bx = blockIdx.x * 32, by = blockIdx.y * 32;
  int tx = threadIdx.x & 31, ty = threadIdx.x >> 5;
#pragma unroll
  for (int i = 0; i < 4; ++i)
    tile[ty + i * 8][tx] = src[(size_t)(bx + ty + i * 8) * cols + by + tx];
  __syncthreads();
#pragma unroll
  for (int i = 0; i < 4; ++i)
    dst[(size_t)(by + ty + i * 8) * rows + bx + tx] = tile[tx][ty + i * 8];
}

// ---------------- flash attention + gate: 8-wave block, LDS-staged K/V, double-buffered ----
// grid(total/128, H). Block = 128 q-rows of one head; wave w owns rows w*16..w*16+15.
// K tile [64][128] and V^T tile [128][64] staged via global_load_lds with XOR-swizzle
// (linear LDS dest + inverse-swizzled global source, swizzled read). 2-phase pipeline:
// stage(t+1) -> compute(t) -> barrier. q pre-scaled by (1/sqrt(D))*log2(e).
__global__ __launch_bounds__(512) void k_attn(const u16* __restrict__ qg,  // total x 4096
                                              const u16* __restrict__ kb,  // total x 512
                                              const u16* __restrict__ vt,  // 512 x total
                                              u16* __restrict__ outg,      // total x 2048
                                              const int* __restrict__ cu, int n_seq, int total) {
  __shared__ __align__(16) u16 Ks[2][64 * 128];   // 32 KB
  __shared__ __align__(16) u16 Vs[2][128 * 64];   // 32 KB
  __shared__ __align__(16) u16 Ps[8][16][72];     // 18 KB, per-wave P bounce
  const int tid = threadIdx.x, lane = tid & 63, w = tid >> 6;  // w = 0..7
  const int h = blockIdx.y, kh = h >> 2;
  const int g = lane >> 4, l15 = lane & 15;

  // heavy-first remap (deepest causal 128-row blocks dispatched first)
  int bx = blockIdx.x, qt = bx;
  int nbx = gridDim.x;
  int per = total / n_seq;
  if (per * n_seq == total && (per & 127) == 0 && nbx % n_seq == 0) {
    int tps = per >> 7;
    int seg = bx % n_seq;
    qt = seg * tps + (tps - 1 - bx / n_seq);
  }
  const int qb0 = qt * 128;

  int seg_start = 0, seg_end = total;
  for (int s = 0; s < n_seq; ++s) {
    int a = cu[s], b = cu[s + 1];
    if (qb0 >= a && qb0 < b) { seg_start = a; seg_end = b; }
  }
  const int qr0 = qb0 + w * 16;
  const int qrow = qr0 + l15;

  // Q as B-fragment: col = q = l15, k = d
  bf16x8 qf[4];
#pragma unroll
  for (int cc = 0; cc < 4; ++cc)
    qf[cc] = *reinterpret_cast<const bf16x8*>(qg + (size_t)qrow * 4096 + h * 256 + cc * 32 + g * 8);

  int blk_end = qb0 + 128; if (blk_end > seg_end) blk_end = seg_end;
  const int NT = (blk_end - seg_start + 63) >> 6;      // tiles staged by the block
  int my_end = qr0 + 16; if (my_end > seg_end) my_end = seg_end;
  const int myNT = (my_end - seg_start + 63) >> 6;     // tiles this wave computes

  f32x4 o[8] = {};                  // O^T: lane q = l15, d = db*16 + g*4 + reg
  float mrow = -1e30f, lrow = 0.f;

  // prologue: stage tile 0 into buffer 0
  {
    const int kv0 = seg_start;
#pragma unroll
    for (int i = 0; i < 2; ++i) {
      int c = i * 512 + tid;
      int r = c >> 4, k16 = c & 15;     // K: 64 rows x 16 chunks of 16B
      async16(kb + (size_t)(kv0 + r) * 512 + kh * 128 + ((k16 ^ (r & 7)) << 3),
              (char*)Ks[0] + c * 16);
      int rv = c >> 3, c8 = c & 7;      // V: 128 rows x 8 chunks of 16B
      async16(vt + (size_t)(kh * 128 + rv) * total + kv0 + ((c8 ^ (rv & 7)) << 3),
              (char*)Vs[0] + c * 16);
    }
  }
  __syncthreads();

  int cur = 0;
  for (int t = 0; t < NT; ++t) {
    if (t + 1 < NT) {                    // issue next-tile staging (latency hides under compute)
      const int kv0 = seg_start + (t + 1) * 64;
#pragma unroll
      for (int i = 0; i < 2; ++i) {
        int c = i * 512 + tid;
        int r = c >> 4, k16 = c & 15;
        async16(kb + (size_t)(kv0 + r) * 512 + kh * 128 + ((k16 ^ (r & 7)) << 3),
                (char*)Ks[cur ^ 1] + c * 16);
        int rv = c >> 3, c8 = c & 7;
        async16(vt + (size_t)(kh * 128 + rv) * total + kv0 + ((c8 ^ (rv & 7)) << 3),
                (char*)Vs[cur ^ 1] + c * 16);
      }
    }
    if (t < myNT) {                      // wave-uniform causal guard
      const int kv0 = seg_start + t * 64;
      f32x4 sa[4] = {};
      __builtin_amdgcn_s_setprio(1);
#pragma unroll
      for (int cc = 0; cc < 4; ++cc)
#pragma unroll
        for (int s = 0; s < 4; ++s) {
          bf16x8 kf = *reinterpret_cast<const bf16x8*>(
              (char*)Ks[cur] + (s * 16 + l15) * 256 + ((((cc << 2) | g) ^ (l15 & 7)) << 4));
          sa[s] = __builtin_amdgcn_mfma_f32_16x16x32_bf16(kf, qf[cc], sa[s], 0, 0, 0);
        }
      __builtin_amdgcn_s_setprio(0);
      float sv[16];
#pragma unroll
      for (int s = 0; s < 4; ++s)
#pragma unroll
        for (int j = 0; j < 4; ++j)
          sv[s * 4 + j] = (kv0 + s * 16 + g * 4 + j > qrow) ? -1e30f : sa[s][j];
      float pm = sv[0];
#pragma unroll
      for (int j = 1; j < 16; ++j) pm = fmaxf(pm, sv[j]);
      pm = fmaxf(pm, __shfl_xor(pm, 16));
      pm = fmaxf(pm, __shfl_xor(pm, 32));
      if (pm > mrow + 11.5f) {           // defer-max (~8 nats, log2 domain)
        float fs = __builtin_amdgcn_exp2f(mrow - pm);
        lrow *= fs;
#pragma unroll
        for (int db = 0; db < 8; ++db)
#pragma unroll
          for (int j = 0; j < 4; ++j) o[db][j] *= fs;
        mrow = pm;
      }
      float p[16];
#pragma unroll
      for (int j = 0; j < 16; ++j)
        p[j] = (sv[j] > -1e29f) ? __builtin_amdgcn_exp2f(sv[j] - mrow) : 0.0f;
      float ps = 0.f;
#pragma unroll
      for (int j = 0; j < 16; ++j) ps += p[j];
      ps += __shfl_xor(ps, 16);
      ps += __shfl_xor(ps, 32);
      lrow += ps;
#pragma unroll
      for (int s = 0; s < 4; ++s) {
        uint2 pw = { pk2(p[s * 4], p[s * 4 + 1]), pk2(p[s * 4 + 2], p[s * 4 + 3]) };
        *reinterpret_cast<uint2*>(&Ps[w][l15][s * 16 + g * 4]) = pw;
      }
      asm volatile("" ::: "memory");     // in-wave DS write->read ordering
      __builtin_amdgcn_s_setprio(1);
#pragma unroll
      for (int half = 0; half < 2; ++half) {
        bf16x8 pf = *reinterpret_cast<const bf16x8*>(&Ps[w][l15][half * 32 + g * 8]);
#pragma unroll
        for (int db = 0; db < 8; ++db) {
          bf16x8 vf = *reinterpret_cast<const bf16x8*>(
              (char*)Vs[cur] + (db * 16 + l15) * 128 + ((((half << 2) | g) ^ (l15 & 7)) << 4));
          o[db] = __builtin_amdgcn_mfma_f32_16x16x32_bf16(vf, pf, o[db], 0, 0, 0);  // O^T
        }
      }
      __builtin_amdgcn_s_setprio(0);
    }
    __syncthreads();                     // drains staging + separates buffer reuse
    cur ^= 1;
  }

  // epilogue: each wave owns its 16 q-rows fully
  const float invL = 1.0f / lrow;
#pragma unroll
  for (int db = 0; db < 8; ++db) {
    int d0 = db * 16 + g * 4;
    uint2 gw = *reinterpret_cast<const uint2*>(qg + (size_t)qrow * 4096 + h * 256 + 128 + d0);
    u16 gu[4] = { (u16)(gw.x & 0xffff), (u16)(gw.x >> 16),
                  (u16)(gw.y & 0xffff), (u16)(gw.y >> 16) };
    u16 ou[4];
#pragma unroll
    for (int j = 0; j < 4; ++j) {
      float gate = b2f(gu[j]);
      float sig = 1.0f / (1.0f + __expf(-gate));
      ou[j] = f2b(o[db][j] * invL * sig);
    }
    *reinterpret_cast<uint2*>(outg + (size_t)qrow * 2048 + h * 128 + d0) =
        *reinterpret_cast<uint2*>(ou);
  }
}

extern "C" void kernel_launch(void* const* d_in, const int* in_sizes, int n_in,
                              void* d_out, int out_size, void* d_ws, size_t ws_size,
                              hipStream_t stream) {
  const float* x    = (const float*)d_in[0];
  const float* cosb = (const float*)d_in[1];
  const float* sinb = (const float*)d_in[2];
  const float* Wq   = (const float*)d_in[3];
  const float* Wk   = (const float*)d_in[4];
  const float* Wv   = (const float*)d_in[5];
  const float* Wo   = (const float*)d_in[6];
  const float* qnw  = (const float*)d_in[7];
  const float* knw  = (const float*)d_in[8];
  const int*   cu   = (const int*)d_in[9];
  const int n_seq = in_sizes[9] - 1;

  const int hidden = 2048, H = 16, KVH = 4, D = 128;
  const int total = in_sizes[0] / hidden;  // 4096
  const int NQ = H * D * 2;                // 4096
  const int NKV = KVH * D;                 // 512

  char* ws = (char*)d_ws;
  size_t off = 0;
  auto alloc = [&](size_t elems) {
    u16* p = (u16*)(ws + off);
    off += elems * 2;
    off = (off + 255) & ~(size_t)255;
    return p;
  };
  u16* xb   = alloc((size_t)total * hidden);
  u16* Wqb  = alloc((size_t)NQ * hidden);
  u16* Wkb  = alloc((size_t)NKV * hidden);
  u16* Wvb  = alloc((size_t)NKV * hidden);
  u16* Wob  = alloc((size_t)hidden * (H * D));
  u16* qgb  = alloc((size_t)total * NQ);
  u16* kbuf = alloc((size_t)total * NKV);
  u16* vbuf = alloc((size_t)total * NKV);
  u16* vtb  = alloc((size_t)total * NKV);
  u16* attg = Wqb;  // alias: Wqb dead after GEMM1

  auto cgrid = [](int n) { int g = (n / 4 + 255) / 256; return g > 2048 ? 2048 : g; };
  k_f2b<<<cgrid(total * hidden), 256, 0, stream>>>(x, xb, total * hidden);
  k_f2b<<<cgrid(NQ * hidden), 256, 0, stream>>>(Wq, Wqb, NQ * hidden);
  k_f2b<<<cgrid(NKV * hidden), 256, 0, stream>>>(Wk, Wkb, NKV * hidden);
  k_f2b<<<cgrid(NKV * hidden), 256, 0, stream>>>(Wv, Wvb, NKV * hidden);
  k_f2b<<<cgrid(hidden * H * D), 256, 0, stream>>>(Wo, Wob, hidden * H * D);

  k_gemm_bf16<<<dim3(NQ / 128, total / 128), 256, 0, stream>>>(xb, Wqb, qgb, total, NQ, hidden);
  k_gemm_kv<<<dim3(NKV / 128, total / 128, 2), 256, 0, stream>>>(xb, Wkb, Wvb, kbuf, vbuf,
                                                                 total, NKV, hidden);
  k_transpose<<<dim3(total / 32, NKV / 32), 256, 0, stream>>>(vbuf, vtb, total, NKV);
  const float qscale = 0.08838834764831845f * 1.4426950408889634f;  // 1/sqrt(D) * log2(e)
  k_normrope<<<total * H / 4, 256, 0, stream>>>(qgb, cosb, sinb, qnw, H, NQ, 2 * D, total, qscale);
  k_normrope<<<total * KVH / 4, 256, 0, stream>>>(kbuf, cosb, sinb, knw, KVH, NKV, D, total, 1.0f);
  k_attn<<<dim3(total / 128, H), 512, 0, stream>>>(qgb, kbuf, vtb, attg, cu, n_seq, total);
  k_gemm_f32<<<dim3(hidden / 128, total / 128), 256, 0, stream>>>(attg, Wob, (float*)d_out,
                                                                  total, hidden, H * D);
}

// Round 7
// 295.434 us; speedup vs baseline: 1.3156x; 1.0327x over previous
//
#include <hip/hip_runtime.h>
#include <stdint.h>

typedef unsigned short u16;
typedef __bf16 bf16_t;
typedef bf16_t bf16x8 __attribute__((ext_vector_type(8)));
typedef float f32x4 __attribute__((ext_vector_type(4)));

__device__ __forceinline__ float b2f(u16 u) {
  union { unsigned int i; float f; } v; v.i = ((unsigned int)u) << 16; return v.f;
}
__device__ __forceinline__ u16 f2b(float f) {
  union { float f; unsigned int i; } v; v.f = f;
  unsigned int r = v.i + 0x7fffu + ((v.i >> 16) & 1u);  // RNE
  return (u16)(r >> 16);
}
__device__ __forceinline__ unsigned int pk2(float a, float b) {
  return (unsigned int)f2b(a) | ((unsigned int)f2b(b) << 16);
}
__device__ __forceinline__ void async16(const void* g, void* lds) {
  __builtin_amdgcn_global_load_lds((const __attribute__((address_space(1))) void*)g,
                                   (__attribute__((address_space(3))) void*)lds,
                                   16, 0, 0);
}

// ---------------- fp32 -> bf16 conversion ----------------
__global__ void k_f2b(const float* __restrict__ src, u16* __restrict__ dst, int n) {
  int i = (blockIdx.x * 256 + threadIdx.x) * 4;
  int stride = gridDim.x * 256 * 4;
  for (; i < n; i += stride) {
    float4 v = *reinterpret_cast<const float4*>(src + i);
    u16 o[4] = { f2b(v.x), f2b(v.y), f2b(v.z), f2b(v.w) };
    *reinterpret_cast<uint2*>(dst + i) = *reinterpret_cast<uint2*>(o);
  }
}

// ---------------- 256x256-tile 8-wave phase-pipelined GEMM ----------------
// C = A(MxK) * B(NxK)^T. BK=64, 4 phases/K-tile, counted vmcnt (never drained in-loop),
// chunk-XOR LDS swizzle (linear gload_lds dest + pre-swizzled global src + swizzled read),
// setprio around MFMA clusters. SPLIT=0: f32 C. SPLIT=1: bf16 C split into q/k/v regions.
#define GPH(P, ...) \
  { \
    bf16x8 af[2][2]; \
    _Pragma("unroll") \
    for (int mi = 0; mi < 2; ++mi) \
      _Pragma("unroll") \
      for (int ks = 0; ks < 2; ++ks) \
        af[mi][ks] = *(const bf16x8*)(abase + (size_t)(l15 + ((P) * 2 + mi) * 16) * 128 + \
                                      ((((ks << 2) | g) ^ (l15 & 7)) << 4)); \
    __VA_ARGS__ \
    asm volatile("" ::: "memory"); \
    __builtin_amdgcn_s_barrier(); \
    asm volatile("" ::: "memory"); \
    __builtin_amdgcn_s_setprio(1); \
    _Pragma("unroll") \
    for (int mi = 0; mi < 2; ++mi) \
      _Pragma("unroll") \
      for (int n = 0; n < 4; ++n) \
        _Pragma("unroll") \
        for (int ks = 0; ks < 2; ++ks) \
          acc[(P) * 2 + mi][n] = __builtin_amdgcn_mfma_f32_16x16x32_bf16( \
              af[mi][ks], bfr[n][ks], acc[(P) * 2 + mi][n], 0, 0, 0); \
    __builtin_amdgcn_s_setprio(0); \
    asm volatile("" ::: "memory"); \
    __builtin_amdgcn_s_barrier(); \
    asm volatile("" ::: "memory"); \
  }

template<int SPLIT>
__global__ __launch_bounds__(512, 2) void k_gemm8(const u16* __restrict__ A,
                                                  const u16* __restrict__ B,
                                                  void* __restrict__ C0,
                                                  u16* __restrict__ Ck, u16* __restrict__ Cv,
                                                  int M, int N, int K, int nqc, int nkc) {
  __shared__ __align__(16) u16 SA[2][2][128 * 64];   // [buf][half] 64 KB
  __shared__ __align__(16) u16 SB[2][2][128 * 64];   // 64 KB
  const int tid = threadIdx.x, lane = tid & 63, w = tid >> 6;
  const int wm = w >> 2, wn = w & 3;                 // 2M x 4N wave grid
  const int g = lane >> 4, l15 = lane & 15;

  int ntx = gridDim.x;
  int id = blockIdx.y * ntx + blockIdx.x;
  int nwg = ntx * gridDim.y;
  if ((nwg & 7) == 0) { int q = nwg >> 3; id = (id & 7) * q + (id >> 3); }  // XCD swizzle
  const int m0 = (id / ntx) * 256, n0 = (id % ntx) * 256;

  const int NT = K >> 6;

  auto stage = [&](u16* dst, const u16* src, int rowbase, int kbase) {
#pragma unroll
    for (int j = 0; j < 2; ++j) {
      int r = j * 64 + (tid >> 3);
      int cpos = tid & 7;
      async16(src + (size_t)(rowbase + r) * K + kbase + ((cpos ^ (r & 7)) << 3),
              (char*)dst + (size_t)(j * 512 + tid) * 16);
    }
  };

  // prologue: A(0), B(0), B(1); leave B(1) in flight
  stage(SA[0][0], A, m0, 0);
  stage(SA[0][1], A, m0 + 128, 0);
  stage(SB[0][0], B, n0, 0);
  stage(SB[0][1], B, n0 + 128, 0);
  if (NT > 1) {
    stage(SB[1][0], B, n0, 64);
    stage(SB[1][1], B, n0 + 128, 64);
    asm volatile("s_waitcnt vmcnt(4)" ::: "memory");
  } else {
    asm volatile("s_waitcnt vmcnt(0)" ::: "memory");
  }
  asm volatile("" ::: "memory");
  __builtin_amdgcn_s_barrier();
  asm volatile("" ::: "memory");

  f32x4 acc[8][4] = {};
  bf16x8 bfr[4][2];

  for (int kt = 0; kt < NT; ++kt) {
    const int cur = kt & 1;
    const char* abase = (const char*)SA[cur][wm];
    const char* bbase = (const char*)SB[cur][wn >> 1];
    const int brow = (wn & 1) * 64 + l15;
    // B-frags for the whole K-tile (front segment of phase 0)
#pragma unroll
    for (int n = 0; n < 4; ++n)
#pragma unroll
      for (int ks = 0; ks < 2; ++ks)
        bfr[n][ks] = *(const bf16x8*)(bbase + (size_t)(brow + n * 16) * 128 +
                                      ((((ks << 2) | g) ^ (l15 & 7)) << 4));
    GPH(0, if (kt + 1 < NT) stage(SA[(kt + 1) & 1][0], A, m0, (kt + 1) * 64);)
    GPH(1, if (kt + 1 < NT) stage(SA[(kt + 1) & 1][1], A, m0 + 128, (kt + 1) * 64);)
    GPH(2, if (kt + 2 < NT) stage(SB[cur][0], B, n0, (kt + 2) * 64);)
    GPH(3,
        if (kt + 2 < NT) {
          stage(SB[cur][1], B, n0 + 128, (kt + 2) * 64);
          asm volatile("s_waitcnt vmcnt(4)" ::: "memory");
        } else {
          asm volatile("s_waitcnt vmcnt(0)" ::: "memory");
        })
  }

  // epilogue
  const int er = g * 4;
  if (SPLIT == 0) {
    float* C = (float*)C0;
#pragma unroll
    for (int m = 0; m < 8; ++m)
#pragma unroll
      for (int n = 0; n < 4; ++n)
#pragma unroll
        for (int jj = 0; jj < 4; ++jj)
          C[(size_t)(m0 + wm * 128 + m * 16 + er + jj) * N + n0 + wn * 64 + n * 16 + l15] =
              acc[m][n][jj];
  } else {
    u16* dst; int stride, coff;
    if (n0 < nqc)            { dst = (u16*)C0; stride = nqc; coff = 0; }
    else if (n0 < nqc + nkc) { dst = Ck;       stride = nkc; coff = nqc; }
    else                     { dst = Cv;       stride = nkc; coff = nqc + nkc; }
#pragma unroll
    for (int m = 0; m < 8; ++m)
#pragma unroll
      for (int n = 0; n < 4; ++n)
#pragma unroll
        for (int jj = 0; jj < 4; ++jj)
          dst[(size_t)(m0 + wm * 128 + m * 16 + er + jj) * stride +
              (n0 - coff) + wn * 64 + n * 16 + l15] = f2b(acc[m][n][jj]);
  }
}

// ---------------- RMSNorm(offset) + RoPE (+ optional post-scale), in place ----------------
__global__ __launch_bounds__(256) void k_normrope(u16* __restrict__ buf,
                                                  const float* __restrict__ cosb,
                                                  const float* __restrict__ sinb,
                                                  const float* __restrict__ w,
                                                  int nheads, int rowstride, int headstride,
                                                  int total, float post_scale) {
  int wid = blockIdx.x * 4 + (threadIdx.x >> 6);
  int lane = threadIdx.x & 63;
  int t = wid / nheads, h = wid - t * nheads;
  if (t >= total) return;
  u16* base = buf + (size_t)t * rowstride + h * headstride;
  float a = b2f(base[lane]), b = b2f(base[lane + 64]);
  float ss = a * a + b * b;
#pragma unroll
  for (int m = 32; m >= 1; m >>= 1) ss += __shfl_xor(ss, m, 64);
  float r = rsqrtf(ss * (1.0f / 128.0f) + 1e-6f);
  float qa = (1.0f + w[lane]) * a * r;
  float qb = (1.0f + w[lane + 64]) * b * r;
  const float* cr = cosb + (size_t)t * 128;
  const float* sr = sinb + (size_t)t * 128;
  float oa = (qa * cr[lane] - qb * sr[lane]) * post_scale;
  float ob = (qb * cr[lane + 64] + qa * sr[lane + 64]) * post_scale;
  base[lane] = f2b(oa);
  base[lane + 64] = f2b(ob);
}

// ---------------- transpose (rows x cols) -> (cols x rows), bf16 ----------------
__global__ __launch_bounds__(256) void k_transpose(const u16* __restrict__ src,
                                                   u16* __restrict__ dst, int rows, int cols) {
  __shared__ u16 tile[32][33];
  int bx = blockIdx.x * 32, by = blockIdx.y * 32;
  int tx = threadIdx.x & 31, ty = threadIdx.x >> 5;
#pragma unroll
  for (int i = 0; i < 4; ++i)
    tile[ty + i * 8][tx] = src[(size_t)(bx + ty + i * 8) * cols + by + tx];
  __syncthreads();
#pragma unroll
  for (int i = 0; i < 4; ++i)
    dst[(size_t)(by + ty + i * 8) * rows + bx + tx] = tile[tx][ty + i * 8];
}

// ---------------- flash attention + gate: 8-wave block, LDS-staged K/V, double-buffered ----
__global__ __launch_bounds__(512) void k_attn(const u16* __restrict__ qg,  // total x 4096
                                              const u16* __restrict__ kb,  // total x 512
                                              const u16* __restrict__ vt,  // 512 x total
                                              u16* __restrict__ outg,      // total x 2048
                                              const int* __restrict__ cu, int n_seq, int total) {
  __shared__ __align__(16) u16 Ks[2][64 * 128];   // 32 KB
  __shared__ __align__(16) u16 Vs[2][128 * 64];   // 32 KB
  __shared__ __align__(16) u16 Ps[8][16][72];     // 18 KB, per-wave P bounce
  const int tid = threadIdx.x, lane = tid & 63, w = tid >> 6;  // w = 0..7
  const int h = blockIdx.y, kh = h >> 2;
  const int g = lane >> 4, l15 = lane & 15;

  // heavy-first remap (deepest causal 128-row blocks dispatched first)
  int bx = blockIdx.x, qt = bx;
  int nbx = gridDim.x;
  int per = total / n_seq;
  if (per * n_seq == total && (per & 127) == 0 && nbx % n_seq == 0) {
    int tps = per >> 7;
    int seg = bx % n_seq;
    qt = seg * tps + (tps - 1 - bx / n_seq);
  }
  const int qb0 = qt * 128;

  int seg_start = 0, seg_end = total;
  for (int s = 0; s < n_seq; ++s) {
    int a = cu[s], b = cu[s + 1];
    if (qb0 >= a && qb0 < b) { seg_start = a; seg_end = b; }
  }
  const int qr0 = qb0 + w * 16;
  const int qrow = qr0 + l15;

  bf16x8 qf[4];
#pragma unroll
  for (int cc = 0; cc < 4; ++cc)
    qf[cc] = *reinterpret_cast<const bf16x8*>(qg + (size_t)qrow * 4096 + h * 256 + cc * 32 + g * 8);

  int blk_end = qb0 + 128; if (blk_end > seg_end) blk_end = seg_end;
  const int NT = (blk_end - seg_start + 63) >> 6;
  int my_end = qr0 + 16; if (my_end > seg_end) my_end = seg_end;
  const int myNT = (my_end - seg_start + 63) >> 6;

  f32x4 o[8] = {};
  float mrow = -1e30f, lrow = 0.f;

  {
    const int kv0 = seg_start;
#pragma unroll
    for (int i = 0; i < 2; ++i) {
      int c = i * 512 + tid;
      int r = c >> 4, k16 = c & 15;
      async16(kb + (size_t)(kv0 + r) * 512 + kh * 128 + ((k16 ^ (r & 7)) << 3),
              (char*)Ks[0] + c * 16);
      int rv = c >> 3, c8 = c & 7;
      async16(vt + (size_t)(kh * 128 + rv) * total + kv0 + ((c8 ^ (rv & 7)) << 3),
              (char*)Vs[0] + c * 16);
    }
  }
  __syncthreads();

  int cur = 0;
  for (int t = 0; t < NT; ++t) {
    if (t + 1 < NT) {
      const int kv0 = seg_start + (t + 1) * 64;
#pragma unroll
      for (int i = 0; i < 2; ++i) {
        int c = i * 512 + tid;
        int r = c >> 4, k16 = c & 15;
        async16(kb + (size_t)(kv0 + r) * 512 + kh * 128 + ((k16 ^ (r & 7)) << 3),
                (char*)Ks[cur ^ 1] + c * 16);
        int rv = c >> 3, c8 = c & 7;
        async16(vt + (size_t)(kh * 128 + rv) * total + kv0 + ((c8 ^ (rv & 7)) << 3),
                (char*)Vs[cur ^ 1] + c * 16);
      }
    }
    if (t < myNT) {
      const int kv0 = seg_start + t * 64;
      f32x4 sa[4] = {};
      __builtin_amdgcn_s_setprio(1);
#pragma unroll
      for (int cc = 0; cc < 4; ++cc)
#pragma unroll
        for (int s = 0; s < 4; ++s) {
          bf16x8 kf = *reinterpret_cast<const bf16x8*>(
              (char*)Ks[cur] + (s * 16 + l15) * 256 + ((((cc << 2) | g) ^ (l15 & 7)) << 4));
          sa[s] = __builtin_amdgcn_mfma_f32_16x16x32_bf16(kf, qf[cc], sa[s], 0, 0, 0);
        }
      __builtin_amdgcn_s_setprio(0);
      float sv[16];
#pragma unroll
      for (int s = 0; s < 4; ++s)
#pragma unroll
        for (int j = 0; j < 4; ++j)
          sv[s * 4 + j] = (kv0 + s * 16 + g * 4 + j > qrow) ? -1e30f : sa[s][j];
      float pm = sv[0];
#pragma unroll
      for (int j = 1; j < 16; ++j) pm = fmaxf(pm, sv[j]);
      pm = fmaxf(pm, __shfl_xor(pm, 16));
      pm = fmaxf(pm, __shfl_xor(pm, 32));
      if (pm > mrow + 11.5f) {
        float fs = __builtin_amdgcn_exp2f(mrow - pm);
        lrow *= fs;
#pragma unroll
        for (int db = 0; db < 8; ++db)
#pragma unroll
          for (int j = 0; j < 4; ++j) o[db][j] *= fs;
        mrow = pm;
      }
      float p[16];
#pragma unroll
      for (int j = 0; j < 16; ++j)
        p[j] = (sv[j] > -1e29f) ? __builtin_amdgcn_exp2f(sv[j] - mrow) : 0.0f;
      float ps = 0.f;
#pragma unroll
      for (int j = 0; j < 16; ++j) ps += p[j];
      ps += __shfl_xor(ps, 16);
      ps += __shfl_xor(ps, 32);
      lrow += ps;
#pragma unroll
      for (int s = 0; s < 4; ++s) {
        uint2 pw = { pk2(p[s * 4], p[s * 4 + 1]), pk2(p[s * 4 + 2], p[s * 4 + 3]) };
        *reinterpret_cast<uint2*>(&Ps[w][l15][s * 16 + g * 4]) = pw;
      }
      asm volatile("" ::: "memory");
      __builtin_amdgcn_s_setprio(1);
#pragma unroll
      for (int half = 0; half < 2; ++half) {
        bf16x8 pf = *reinterpret_cast<const bf16x8*>(&Ps[w][l15][half * 32 + g * 8]);
#pragma unroll
        for (int db = 0; db < 8; ++db) {
          bf16x8 vf = *reinterpret_cast<const bf16x8*>(
              (char*)Vs[cur] + (db * 16 + l15) * 128 + ((((half << 2) | g) ^ (l15 & 7)) << 4));
          o[db] = __builtin_amdgcn_mfma_f32_16x16x32_bf16(vf, pf, o[db], 0, 0, 0);
        }
      }
      __builtin_amdgcn_s_setprio(0);
    }
    __syncthreads();
    cur ^= 1;
  }

  const float invL = 1.0f / lrow;
#pragma unroll
  for (int db = 0; db < 8; ++db) {
    int d0 = db * 16 + g * 4;
    uint2 gw = *reinterpret_cast<const uint2*>(qg + (size_t)qrow * 4096 + h * 256 + 128 + d0);
    u16 gu[4] = { (u16)(gw.x & 0xffff), (u16)(gw.x >> 16),
                  (u16)(gw.y & 0xffff), (u16)(gw.y >> 16) };
    u16 ou[4];
#pragma unroll
    for (int j = 0; j < 4; ++j) {
      float gate = b2f(gu[j]);
      float sig = 1.0f / (1.0f + __expf(-gate));
      ou[j] = f2b(o[db][j] * invL * sig);
    }
    *reinterpret_cast<uint2*>(outg + (size_t)qrow * 2048 + h * 128 + d0) =
        *reinterpret_cast<uint2*>(ou);
  }
}

extern "C" void kernel_launch(void* const* d_in, const int* in_sizes, int n_in,
                              void* d_out, int out_size, void* d_ws, size_t ws_size,
                              hipStream_t stream) {
  const float* x    = (const float*)d_in[0];
  const float* cosb = (const float*)d_in[1];
  const float* sinb = (const float*)d_in[2];
  const float* Wq   = (const float*)d_in[3];
  const float* Wk   = (const float*)d_in[4];
  const float* Wv   = (const float*)d_in[5];
  const float* Wo   = (const float*)d_in[6];
  const float* qnw  = (const float*)d_in[7];
  const float* knw  = (const float*)d_in[8];
  const int*   cu   = (const int*)d_in[9];
  const int n_seq = in_sizes[9] - 1;

  const int hidden = 2048, H = 16, KVH = 4, D = 128;
  const int total = in_sizes[0] / hidden;  // 4096
  const int NQ = H * D * 2;                // 4096
  const int NKV = KVH * D;                 // 512

  char* ws = (char*)d_ws;
  size_t off = 0;
  auto alloc = [&](size_t elems) {
    u16* p = (u16*)(ws + off);
    off += elems * 2;
    off = (off + 255) & ~(size_t)255;
    return p;
  };
  u16* xb   = alloc((size_t)total * hidden);
  u16* Wqb  = alloc((size_t)NQ * hidden);    // Wqb|Wkb|Wvb contiguous => merged B (5120 x 2048)
  u16* Wkb  = alloc((size_t)NKV * hidden);
  u16* Wvb  = alloc((size_t)NKV * hidden);
  u16* Wob  = alloc((size_t)hidden * (H * D));
  u16* qgb  = alloc((size_t)total * NQ);
  u16* kbuf = alloc((size_t)total * NKV);
  u16* vbuf = alloc((size_t)total * NKV);
  u16* vtb  = alloc((size_t)total * NKV);
  u16* attg = Wqb;  // alias: Wqb dead after the qkv GEMM

  auto cgrid = [](int n) { int g = (n / 4 + 255) / 256; return g > 2048 ? 2048 : g; };
  k_f2b<<<cgrid(total * hidden), 256, 0, stream>>>(x, xb, total * hidden);
  k_f2b<<<cgrid(NQ * hidden), 256, 0, stream>>>(Wq, Wqb, NQ * hidden);
  k_f2b<<<cgrid(NKV * hidden), 256, 0, stream>>>(Wk, Wkb, NKV * hidden);
  k_f2b<<<cgrid(NKV * hidden), 256, 0, stream>>>(Wv, Wvb, NKV * hidden);
  k_f2b<<<cgrid(hidden * H * D), 256, 0, stream>>>(Wo, Wob, hidden * H * D);

  // fused qkv projection: C = x @ [Wq|Wk|Wv]^T, split-written to qgb / kbuf / vbuf
  const int Nqkv = NQ + 2 * NKV;  // 5120
  k_gemm8<1><<<dim3(Nqkv / 256, total / 256), 512, 0, stream>>>(
      xb, Wqb, qgb, kbuf, vbuf, total, Nqkv, hidden, NQ, NKV);
  k_transpose<<<dim3(total / 32, NKV / 32), 256, 0, stream>>>(vbuf, vtb, total, NKV);
  const float qscale = 0.08838834764831845f * 1.4426950408889634f;  // 1/sqrt(D) * log2(e)
  k_normrope<<<total * H / 4, 256, 0, stream>>>(qgb, cosb, sinb, qnw, H, NQ, 2 * D, total, qscale);
  k_normrope<<<total * KVH / 4, 256, 0, stream>>>(kbuf, cosb, sinb, knw, KVH, NKV, D, total, 1.0f);
  k_attn<<<dim3(total / 128, H), 512, 0, stream>>>(qgb, kbuf, vtb, attg, cu, n_seq, total);
  // out = attg @ Wo^T (f32 to d_out)
  k_gemm8<0><<<dim3(hidden / 256, total / 256), 512, 0, stream>>>(
      attg, Wob, (float*)d_out, nullptr, nullptr, total, hidden, H * D, 0, 0);
}

// Round 8
// 272.419 us; speedup vs baseline: 1.4268x; 1.0845x over previous
//
#include <hip/hip_runtime.h>
#include <stdint.h>

typedef unsigned short u16;
typedef __bf16 bf16_t;
typedef bf16_t bf16x8 __attribute__((ext_vector_type(8)));
typedef float f32x4 __attribute__((ext_vector_type(4)));

__device__ __forceinline__ float b2f(u16 u) {
  union { unsigned int i; float f; } v; v.i = ((unsigned int)u) << 16; return v.f;
}
__device__ __forceinline__ u16 f2b(float f) {
  union { float f; unsigned int i; } v; v.f = f;
  unsigned int r = v.i + 0x7fffu + ((v.i >> 16) & 1u);  // RNE
  return (u16)(r >> 16);
}
__device__ __forceinline__ unsigned int pk2(float a, float b) {
  return (unsigned int)f2b(a) | ((unsigned int)f2b(b) << 16);
}
__device__ __forceinline__ void async16(const void* g, void* lds) {
  __builtin_amdgcn_global_load_lds((const __attribute__((address_space(1))) void*)g,
                                   (__attribute__((address_space(3))) void*)lds,
                                   16, 0, 0);
}

// ---------------- fp32 -> bf16 conversion ----------------
__global__ void k_f2b(const float* __restrict__ src, u16* __restrict__ dst, int n) {
  int i = (blockIdx.x * 256 + threadIdx.x) * 4;
  int stride = gridDim.x * 256 * 4;
  for (; i < n; i += stride) {
    float4 v = *reinterpret_cast<const float4*>(src + i);
    u16 o[4] = { f2b(v.x), f2b(v.y), f2b(v.z), f2b(v.w) };
    *reinterpret_cast<uint2*>(dst + i) = *reinterpret_cast<uint2*>(o);
  }
}

// ---------------- soft-phase 8-wave GEMM: C = A(MxK) * B(NxK)^T ----------------
// BM=256, BN template (160 for qkv => 512 blocks = 2 exact rounds; 128 for out => 256 = 1 round).
// Wave grid 4M x 2N (per-wave 64 x BN/2). BK=64. One vmcnt(BSTG)+barrier per K-tile; A double-
// buffered (boundary barrier protects), B triple-buffered (staged 2 tiles ahead, counted vmcnt).
// Chunk-XOR LDS swizzle: linear gload_lds dest + inverse-swizzled global src + swizzled ds_read.
template<int BN, int NF, int BSTG, int SPLIT>
__global__ __launch_bounds__(512, 2) void k_gemmS(const u16* __restrict__ A,
                                                  const u16* __restrict__ B,
                                                  void* __restrict__ C0,
                                                  u16* __restrict__ Ck, u16* __restrict__ Cv,
                                                  int M, int N, int K, int nqc, int nkc) {
  __shared__ __align__(16) u16 SA[2][2][128 * 64];   // [buf][half] 64 KB
  __shared__ __align__(16) u16 SB[3][BN * 64];       // 3-buffer rotation
  __shared__ __align__(16) u16 dscr[512];            // dummy sink for stage padding
  const int tid = threadIdx.x, lane = tid & 63, w = tid >> 6;
  const int wm = w >> 1, wn = w & 1;                 // 4M x 2N wave grid
  const int g = lane >> 4, l15 = lane & 15;

  int ntx = gridDim.x;
  int id = blockIdx.y * ntx + blockIdx.x;
  int nwg = ntx * gridDim.y;
  if ((nwg & 7) == 0) { int q = nwg >> 3; id = (id & 7) * q + (id >> 3); }  // XCD swizzle
  const int m0 = (id / ntx) * 256, n0 = (id % ntx) * BN;
  const int NT = K >> 6;

  auto stageA = [&](int buf, int half, int kb) {
#pragma unroll
    for (int j = 0; j < 2; ++j) {
      int c = j * 512 + tid;
      int r = c >> 3, cp = c & 7;
      async16(A + (size_t)(m0 + half * 128 + r) * K + kb + ((cp ^ (r & 7)) << 3),
              (char*)SA[buf][half] + c * 16);
    }
  };
  auto stageB = [&](int buf, int kb) {
#pragma unroll
    for (int j = 0; j < BSTG; ++j) {
      int c = j * 512 + tid;
      if (c < BN * 8) {
        int r = c >> 3, cp = c & 7;
        async16(B + (size_t)(n0 + r) * K + kb + ((cp ^ (r & 7)) << 3),
                (char*)SB[buf] + c * 16);
      } else {
        async16(B, (char*)dscr + lane * 16);  // uniform-count pad (wave-uniform branch)
      }
    }
  };

  // prologue: A(0), B(0), B(1); leave B(1)'s loads in flight
  stageA(0, 0, 0); stageA(0, 1, 0);
  stageB(0, 0);
  if (NT > 1) stageB(1, 64);
  if constexpr (BSTG == 3) asm volatile("s_waitcnt vmcnt(3)" ::: "memory");
  else                     asm volatile("s_waitcnt vmcnt(2)" ::: "memory");
  __builtin_amdgcn_s_barrier();
  asm volatile("" ::: "memory");

  f32x4 acc[4][NF] = {};
  int c3 = 0;                                        // kt % 3
  for (int kt = 0; kt < NT; ++kt) {
    const int cur = kt & 1;
    const char* bb = (const char*)SB[c3];
    bf16x8 bfr[NF][2];
#pragma unroll
    for (int n = 0; n < NF; ++n)
#pragma unroll
      for (int ks = 0; ks < 2; ++ks)
        bfr[n][ks] = *(const bf16x8*)(bb + (size_t)(wn * (BN / 2) + n * 16 + l15) * 128 +
                                      ((((ks << 2) | g) ^ (l15 & 7)) << 4));
    if (kt + 1 < NT) { stageA(cur ^ 1, 0, (kt + 1) * 64); stageA(cur ^ 1, 1, (kt + 1) * 64); }
    const char* ab = (const char*)SA[cur][wm >> 1];
    const int rb = (wm & 1) * 64;
#pragma unroll
    for (int m = 0; m < 4; ++m) {
      bf16x8 af[2];
#pragma unroll
      for (int ks = 0; ks < 2; ++ks)
        af[ks] = *(const bf16x8*)(ab + (size_t)(rb + m * 16 + l15) * 128 +
                                  ((((ks << 2) | g) ^ (l15 & 7)) << 4));
      __builtin_amdgcn_s_setprio(1);
#pragma unroll
      for (int n = 0; n < NF; ++n)
#pragma unroll
        for (int ks = 0; ks < 2; ++ks)
          acc[m][n] = __builtin_amdgcn_mfma_f32_16x16x32_bf16(af[ks], bfr[n][ks], acc[m][n],
                                                              0, 0, 0);
      __builtin_amdgcn_s_setprio(0);
    }
    int b2 = c3 + 2; if (b2 >= 3) b2 -= 3;
    if (kt + 2 < NT) stageB(b2, (kt + 2) * 64);
    asm volatile("" ::: "memory");
    if (kt + 2 < NT) {
      if constexpr (BSTG == 3) asm volatile("s_waitcnt vmcnt(3)" ::: "memory");
      else                     asm volatile("s_waitcnt vmcnt(2)" ::: "memory");
    } else {
      asm volatile("s_waitcnt vmcnt(0)" ::: "memory");
    }
    __builtin_amdgcn_s_barrier();
    asm volatile("" ::: "memory");
    c3 = (c3 == 2) ? 0 : c3 + 1;
  }

  // epilogue: row = m0 + wm*64 + m*16 + g*4 + jj, col = n0 + wn*(BN/2) + n*16 + l15
  const int er = g * 4;
  if constexpr (SPLIT == 0) {
    float* C = (float*)C0;
#pragma unroll
    for (int m = 0; m < 4; ++m)
#pragma unroll
      for (int n = 0; n < NF; ++n)
#pragma unroll
        for (int jj = 0; jj < 4; ++jj)
          C[(size_t)(m0 + wm * 64 + m * 16 + er + jj) * N + n0 + wn * (BN / 2) + n * 16 + l15] =
              acc[m][n][jj];
  } else {
#pragma unroll
    for (int n = 0; n < NF; ++n) {
      int col0 = n0 + wn * (BN / 2) + n * 16;        // 16-col frag never straddles a region
      u16* dst; int stride, coff;
      if (col0 < nqc)            { dst = (u16*)C0; stride = nqc; coff = 0; }
      else if (col0 < nqc + nkc) { dst = Ck;       stride = nkc; coff = nqc; }
      else                       { dst = Cv;       stride = nkc; coff = nqc + nkc; }
#pragma unroll
      for (int m = 0; m < 4; ++m)
#pragma unroll
        for (int jj = 0; jj < 4; ++jj)
          dst[(size_t)(m0 + wm * 64 + m * 16 + er + jj) * stride + (col0 - coff) + l15] =
              f2b(acc[m][n][jj]);
    }
  }
}

// ---------------- RMSNorm(offset) + RoPE (+ optional post-scale), in place ----------------
__global__ __launch_bounds__(256) void k_normrope(u16* __restrict__ buf,
                                                  const float* __restrict__ cosb,
                                                  const float* __restrict__ sinb,
                                                  const float* __restrict__ w,
                                                  int nheads, int rowstride, int headstride,
                                                  int total, float post_scale) {
  int wid = blockIdx.x * 4 + (threadIdx.x >> 6);
  int lane = threadIdx.x & 63;
  int t = wid / nheads, h = wid - t * nheads;
  if (t >= total) return;
  u16* base = buf + (size_t)t * rowstride + h * headstride;
  float a = b2f(base[lane]), b = b2f(base[lane + 64]);
  float ss = a * a + b * b;
#pragma unroll
  for (int m = 32; m >= 1; m >>= 1) ss += __shfl_xor(ss, m, 64);
  float r = rsqrtf(ss * (1.0f / 128.0f) + 1e-6f);
  float qa = (1.0f + w[lane]) * a * r;
  float qb = (1.0f + w[lane + 64]) * b * r;
  const float* cr = cosb + (size_t)t * 128;
  const float* sr = sinb + (size_t)t * 128;
  float oa = (qa * cr[lane] - qb * sr[lane]) * post_scale;
  float ob = (qb * cr[lane + 64] + qa * sr[lane + 64]) * post_scale;
  base[lane] = f2b(oa);
  base[lane + 64] = f2b(ob);
}

// ---------------- transpose (rows x cols) -> (cols x rows), bf16 ----------------
__global__ __launch_bounds__(256) void k_transpose(const u16* __restrict__ src,
                                                   u16* __restrict__ dst, int rows, int cols) {
  __shared__ u16 tile[32][33];
  int bx = blockIdx.x * 32, by = blockIdx.y * 32;
  int tx = threadIdx.x & 31, ty = threadIdx.x >> 5;
#pragma unroll
  for (int i = 0; i < 4; ++i)
    tile[ty + i * 8][tx] = src[(size_t)(bx + ty + i * 8) * cols + by + tx];
  __syncthreads();
#pragma unroll
  for (int i = 0; i < 4; ++i)
    dst[(size_t)(by + ty + i * 8) * rows + bx + tx] = tile[tx][ty + i * 8];
}

// ---------------- flash attention + gate: 8-wave block, LDS-staged K/V, double-buffered ----
__global__ __launch_bounds__(512) void k_attn(const u16* __restrict__ qg,  // total x 4096
                                              const u16* __restrict__ kb,  // total x 512
                                              const u16* __restrict__ vt,  // 512 x total
                                              u16* __restrict__ outg,      // total x 2048
                                              const int* __restrict__ cu, int n_seq, int total) {
  __shared__ __align__(16) u16 Ks[2][64 * 128];   // 32 KB
  __shared__ __align__(16) u16 Vs[2][128 * 64];   // 32 KB
  __shared__ __align__(16) u16 Ps[8][16][72];     // 18 KB, per-wave P bounce
  const int tid = threadIdx.x, lane = tid & 63, w = tid >> 6;  // w = 0..7
  const int h = blockIdx.y, kh = h >> 2;
  const int g = lane >> 4, l15 = lane & 15;

  int bx = blockIdx.x, qt = bx;
  int nbx = gridDim.x;
  int per = total / n_seq;
  if (per * n_seq == total && (per & 127) == 0 && nbx % n_seq == 0) {
    int tps = per >> 7;
    int seg = bx % n_seq;
    qt = seg * tps + (tps - 1 - bx / n_seq);
  }
  const int qb0 = qt * 128;

  int seg_start = 0, seg_end = total;
  for (int s = 0; s < n_seq; ++s) {
    int a = cu[s], b = cu[s + 1];
    if (qb0 >= a && qb0 < b) { seg_start = a; seg_end = b; }
  }
  const int qr0 = qb0 + w * 16;
  const int qrow = qr0 + l15;

  bf16x8 qf[4];
#pragma unroll
  for (int cc = 0; cc < 4; ++cc)
    qf[cc] = *reinterpret_cast<const bf16x8*>(qg + (size_t)qrow * 4096 + h * 256 + cc * 32 + g * 8);

  int blk_end = qb0 + 128; if (blk_end > seg_end) blk_end = seg_end;
  const int NT = (blk_end - seg_start + 63) >> 6;
  int my_end = qr0 + 16; if (my_end > seg_end) my_end = seg_end;
  const int myNT = (my_end - seg_start + 63) >> 6;

  f32x4 o[8] = {};
  float mrow = -1e30f, lrow = 0.f;

  {
    const int kv0 = seg_start;
#pragma unroll
    for (int i = 0; i < 2; ++i) {
      int c = i * 512 + tid;
      int r = c >> 4, k16 = c & 15;
      async16(kb + (size_t)(kv0 + r) * 512 + kh * 128 + ((k16 ^ (r & 7)) << 3),
              (char*)Ks[0] + c * 16);
      int rv = c >> 3, c8 = c & 7;
      async16(vt + (size_t)(kh * 128 + rv) * total + kv0 + ((c8 ^ (rv & 7)) << 3),
              (char*)Vs[0] + c * 16);
    }
  }
  __syncthreads();

  int cur = 0;
  for (int t = 0; t < NT; ++t) {
    if (t + 1 < NT) {
      const int kv0 = seg_start + (t + 1) * 64;
#pragma unroll
      for (int i = 0; i < 2; ++i) {
        int c = i * 512 + tid;
        int r = c >> 4, k16 = c & 15;
        async16(kb + (size_t)(kv0 + r) * 512 + kh * 128 + ((k16 ^ (r & 7)) << 3),
                (char*)Ks[cur ^ 1] + c * 16);
        int rv = c >> 3, c8 = c & 7;
        async16(vt + (size_t)(kh * 128 + rv) * total + kv0 + ((c8 ^ (rv & 7)) << 3),
                (char*)Vs[cur ^ 1] + c * 16);
      }
    }
    if (t < myNT) {
      const int kv0 = seg_start + t * 64;
      f32x4 sa[4] = {};
      __builtin_amdgcn_s_setprio(1);
#pragma unroll
      for (int cc = 0; cc < 4; ++cc)
#pragma unroll
        for (int s = 0; s < 4; ++s) {
          bf16x8 kf = *reinterpret_cast<const bf16x8*>(
              (char*)Ks[cur] + (s * 16 + l15) * 256 + ((((cc << 2) | g) ^ (l15 & 7)) << 4));
          sa[s] = __builtin_amdgcn_mfma_f32_16x16x32_bf16(kf, qf[cc], sa[s], 0, 0, 0);
        }
      __builtin_amdgcn_s_setprio(0);
      float sv[16];
#pragma unroll
      for (int s = 0; s < 4; ++s)
#pragma unroll
        for (int j = 0; j < 4; ++j)
          sv[s * 4 + j] = (kv0 + s * 16 + g * 4 + j > qrow) ? -1e30f : sa[s][j];
      float pm = sv[0];
#pragma unroll
      for (int j = 1; j < 16; ++j) pm = fmaxf(pm, sv[j]);
      pm = fmaxf(pm, __shfl_xor(pm, 16));
      pm = fmaxf(pm, __shfl_xor(pm, 32));
      if (pm > mrow + 11.5f) {
        float fs = __builtin_amdgcn_exp2f(mrow - pm);
        lrow *= fs;
#pragma unroll
        for (int db = 0; db < 8; ++db)
#pragma unroll
          for (int j = 0; j < 4; ++j) o[db][j] *= fs;
        mrow = pm;
      }
      float p[16];
#pragma unroll
      for (int j = 0; j < 16; ++j)
        p[j] = (sv[j] > -1e29f) ? __builtin_amdgcn_exp2f(sv[j] - mrow) : 0.0f;
      float ps = 0.f;
#pragma unroll
      for (int j = 0; j < 16; ++j) ps += p[j];
      ps += __shfl_xor(ps, 16);
      ps += __shfl_xor(ps, 32);
      lrow += ps;
#pragma unroll
      for (int s = 0; s < 4; ++s) {
        uint2 pw = { pk2(p[s * 4], p[s * 4 + 1]), pk2(p[s * 4 + 2], p[s * 4 + 3]) };
        *reinterpret_cast<uint2*>(&Ps[w][l15][s * 16 + g * 4]) = pw;
      }
      asm volatile("" ::: "memory");
      __builtin_amdgcn_s_setprio(1);
#pragma unroll
      for (int half = 0; half < 2; ++half) {
        bf16x8 pf = *reinterpret_cast<const bf16x8*>(&Ps[w][l15][half * 32 + g * 8]);
#pragma unroll
        for (int db = 0; db < 8; ++db) {
          bf16x8 vf = *reinterpret_cast<const bf16x8*>(
              (char*)Vs[cur] + (db * 16 + l15) * 128 + ((((half << 2) | g) ^ (l15 & 7)) << 4));
          o[db] = __builtin_amdgcn_mfma_f32_16x16x32_bf16(vf, pf, o[db], 0, 0, 0);
        }
      }
      __builtin_amdgcn_s_setprio(0);
    }
    __syncthreads();
    cur ^= 1;
  }

  const float invL = 1.0f / lrow;
#pragma unroll
  for (int db = 0; db < 8; ++db) {
    int d0 = db * 16 + g * 4;
    uint2 gw = *reinterpret_cast<const uint2*>(qg + (size_t)qrow * 4096 + h * 256 + 128 + d0);
    u16 gu[4] = { (u16)(gw.x & 0xffff), (u16)(gw.x >> 16),
                  (u16)(gw.y & 0xffff), (u16)(gw.y >> 16) };
    u16 ou[4];
#pragma unroll
    for (int j = 0; j < 4; ++j) {
      float gate = b2f(gu[j]);
      float sig = 1.0f / (1.0f + __expf(-gate));
      ou[j] = f2b(o[db][j] * invL * sig);
    }
    *reinterpret_cast<uint2*>(outg + (size_t)qrow * 2048 + h * 128 + d0) =
        *reinterpret_cast<uint2*>(ou);
  }
}

extern "C" void kernel_launch(void* const* d_in, const int* in_sizes, int n_in,
                              void* d_out, int out_size, void* d_ws, size_t ws_size,
                              hipStream_t stream) {
  const float* x    = (const float*)d_in[0];
  const float* cosb = (const float*)d_in[1];
  const float* sinb = (const float*)d_in[2];
  const float* Wq   = (const float*)d_in[3];
  const float* Wk   = (const float*)d_in[4];
  const float* Wv   = (const float*)d_in[5];
  const float* Wo   = (const float*)d_in[6];
  const float* qnw  = (const float*)d_in[7];
  const float* knw  = (const float*)d_in[8];
  const int*   cu   = (const int*)d_in[9];
  const int n_seq = in_sizes[9] - 1;

  const int hidden = 2048, H = 16, KVH = 4, D = 128;
  const int total = in_sizes[0] / hidden;  // 4096
  const int NQ = H * D * 2;                // 4096
  const int NKV = KVH * D;                 // 512

  char* ws = (char*)d_ws;
  size_t off = 0;
  auto alloc = [&](size_t elems) {
    u16* p = (u16*)(ws + off);
    off += elems * 2;
    off = (off + 255) & ~(size_t)255;
    return p;
  };
  u16* xb   = alloc((size_t)total * hidden);
  u16* Wqb  = alloc((size_t)NQ * hidden);    // Wqb|Wkb|Wvb contiguous => merged B (5120 x 2048)
  u16* Wkb  = alloc((size_t)NKV * hidden);
  u16* Wvb  = alloc((size_t)NKV * hidden);
  u16* Wob  = alloc((size_t)hidden * (H * D));
  u16* qgb  = alloc((size_t)total * NQ);
  u16* kbuf = alloc((size_t)total * NKV);
  u16* vbuf = alloc((size_t)total * NKV);
  u16* vtb  = alloc((size_t)total * NKV);
  u16* attg = Wqb;  // alias: Wqb dead after the qkv GEMM

  auto cgrid = [](int n) { int g = (n / 4 + 255) / 256; return g > 2048 ? 2048 : g; };
  k_f2b<<<cgrid(total * hidden), 256, 0, stream>>>(x, xb, total * hidden);
  k_f2b<<<cgrid(NQ * hidden), 256, 0, stream>>>(Wq, Wqb, NQ * hidden);
  k_f2b<<<cgrid(NKV * hidden), 256, 0, stream>>>(Wk, Wkb, NKV * hidden);
  k_f2b<<<cgrid(NKV * hidden), 256, 0, stream>>>(Wv, Wvb, NKV * hidden);
  k_f2b<<<cgrid(hidden * H * D), 256, 0, stream>>>(Wo, Wob, hidden * H * D);

  // fused qkv projection: C = x @ [Wq|Wk|Wv]^T; BN=160 => 16x32 = 512 blocks = 2 exact rounds
  const int Nqkv = NQ + 2 * NKV;  // 5120
  k_gemmS<160, 5, 3, 1><<<dim3(Nqkv / 160, total / 256), 512, 0, stream>>>(
      xb, Wqb, qgb, kbuf, vbuf, total, Nqkv, hidden, NQ, NKV);
  k_transpose<<<dim3(total / 32, NKV / 32), 256, 0, stream>>>(vbuf, vtb, total, NKV);
  const float qscale = 0.08838834764831845f * 1.4426950408889634f;  // 1/sqrt(D) * log2(e)
  k_normrope<<<total * H / 4, 256, 0, stream>>>(qgb, cosb, sinb, qnw, H, NQ, 2 * D, total, qscale);
  k_normrope<<<total * KVH / 4, 256, 0, stream>>>(kbuf, cosb, sinb, knw, KVH, NKV, D, total, 1.0f);
  k_attn<<<dim3(total / 128, H), 512, 0, stream>>>(qgb, kbuf, vtb, attg, cu, n_seq, total);
  // out = attg @ Wo^T; BN=128 => 16x16 = 256 blocks = 1 exact round
  k_gemmS<128, 4, 2, 0><<<dim3(hidden / 128, total / 256), 512, 0, stream>>>(
      attg, Wob, (float*)d_out, nullptr, nullptr, total, hidden, H * D, 0, 0);
}